// Round 11
// baseline (131.454 us; speedup 1.0000x reference)
//
#include <hip/hip_runtime.h>
#include <math.h>

#define S_LEN 2048
#define HID   1024
#define NH    16
#define HD    64
#define NM    128
#define CAUG  192

constexpr float ALPHA = 0.9f;

typedef __attribute__((ext_vector_type(8))) short bf16x8;
typedef __attribute__((ext_vector_type(4))) short bf16x4;
typedef __attribute__((ext_vector_type(4))) float f32x4;
typedef __attribute__((ext_vector_type(4))) int   int4v;

#define MFMA(a,b,c) __builtin_amdgcn_mfma_f32_16x16x32_bf16(a,b,c,0,0,0)

static __device__ inline short f2bf(float f) {
    unsigned u = __float_as_uint(f);
    u += 0x7fffu + ((u >> 16) & 1u);      // RNE
    return (short)(u >> 16);
}
static __device__ inline float bf2f(short s) {
    return __uint_as_float(((unsigned)(unsigned short)s) << 16);
}

// ---------------------------------------------------------------------------
// fp32 -> bf16 conversion: hs + 4 weights, float4-wide; tail range does the
// omega [h][d][m] -> om_t bf16 [h][m][d] transpose.
// ---------------------------------------------------------------------------
__global__ __launch_bounds__(256)
void conv_kernel(const float* __restrict__ hs,
                 const float* __restrict__ Wq, const float* __restrict__ Wk,
                 const float* __restrict__ Wv, const float* __restrict__ Wo,
                 const float* __restrict__ omega,
                 short* __restrict__ hsb, short* __restrict__ wqb, short* __restrict__ wkb,
                 short* __restrict__ wvb, short* __restrict__ wob, short* __restrict__ omtb)
{
    int i = blockIdx.x * 256 + threadIdx.x;           // f4-unit index
    if (i >= 1605632) return;
    if (i >= 1572864) {                               // omega transpose tail
        int j = (i - 1572864) * 4;                    // elem index in [h][d][m]
        int h = j >> 13, rem = j & 8191;
        int d = rem >> 7, m = rem & 127;
        float4 v = *(const float4*)(omega + j);       // 4 consecutive m
        short* dst = omtb + ((h * 128 + m) << 6) + d; // [h][m][d]
        dst[0]       = f2bf(v.x);
        dst[64]      = f2bf(v.y);
        dst[128]     = f2bf(v.z);
        dst[192]     = f2bf(v.w);
        return;
    }
    const float* src; short* dst; int off;
    if (i < 524288) { src = hs; dst = hsb; off = i; }
    else {
        int j = i - 524288;
        int r = j >> 18;              // 0..3
        off = j & 262143;
        src = (r == 0) ? Wq : (r == 1) ? Wk : (r == 2) ? Wv : Wo;
        dst = (r == 0) ? wqb : (r == 1) ? wkb : (r == 2) ? wvb : wob;
    }
    float4 v = ((const float4*)src)[off];
    bf16x4 o; o[0] = f2bf(v.x); o[1] = f2bf(v.y); o[2] = f2bf(v.z); o[3] = f2bf(v.w);
    ((bf16x4*)dst)[off] = o;
}

// ---------------------------------------------------------------------------
// bf16 MFMA GEMM: C = A(2048x1024) @ W(1024x1024)^T + bias
// BM=64, BN=128, BK=32; 4 waves 2(m)x2(n), wave tile 32x64, acc[2][4].
// mode 0: C bf16 [m][1024];  mode 1: C bf16 transposed [n][Mrows];  mode 2: C f32
// ---------------------------------------------------------------------------
__global__ __launch_bounds__(256)
void gemm_mfma(const short* __restrict__ A,
               const short* __restrict__ W0, const float* __restrict__ b0, void* C0,
               const short* __restrict__ W1, const float* __restrict__ b1, void* C1,
               const short* __restrict__ W2, const float* __restrict__ b2, void* C2,
               int m0_, int m1_, int m2_, int Mrows)
{
    const short* W; const float* bias; void* C; int mode;
    if (blockIdx.z == 0)      { W = W0; bias = b0; C = C0; mode = m0_; }
    else if (blockIdx.z == 1) { W = W1; bias = b1; C = C1; mode = m1_; }
    else                      { W = W2; bias = b2; C = C2; mode = m2_; }

    __shared__ short As[64][40];
    __shared__ short Bs[128][40];

    const int tid = threadIdx.x;
    const int wave = tid >> 6, lane = tid & 63;
    const int l15 = lane & 15, l4 = lane >> 4;
    const int wm = wave >> 1, wn = wave & 1;
    const int m0 = blockIdx.y * 64, n0 = blockIdx.x * 128;

    const int srow = tid >> 2;
    const int scol = (tid & 3) * 16;

    f32x4 acc[2][4];
#pragma unroll
    for (int i = 0; i < 2; ++i)
#pragma unroll
        for (int j = 0; j < 4; ++j) acc[i][j] = (f32x4){0.f,0.f,0.f,0.f};

    int4v apre, bpre0, bpre1;
    apre  = *(const int4v*)((const char*)A + (size_t)(m0 + srow) * 2048 + scol);
    bpre0 = *(const int4v*)((const char*)W + (size_t)(n0 + srow) * 2048 + scol);
    bpre1 = *(const int4v*)((const char*)W + (size_t)(n0 + 64 + srow) * 2048 + scol);

    for (int ks = 0; ks < 32; ++ks) {
        __syncthreads();
        *(int4v*)((char*)&As[0][0] + srow * 80 + scol) = apre;
        *(int4v*)((char*)&Bs[0][0] + srow * 80 + scol) = bpre0;
        *(int4v*)((char*)&Bs[0][0] + (64 + srow) * 80 + scol) = bpre1;
        __syncthreads();
        if (ks + 1 < 32) {
            const int kb = (ks + 1) * 64;
            apre  = *(const int4v*)((const char*)A + (size_t)(m0 + srow) * 2048 + kb + scol);
            bpre0 = *(const int4v*)((const char*)W + (size_t)(n0 + srow) * 2048 + kb + scol);
            bpre1 = *(const int4v*)((const char*)W + (size_t)(n0 + 64 + srow) * 2048 + kb + scol);
        }
        bf16x8 af[2], bf[4];
#pragma unroll
        for (int mi = 0; mi < 2; ++mi)
            af[mi] = *(const bf16x8*)((const char*)&As[0][0] + (wm*32 + mi*16 + l15) * 80 + l4*16);
#pragma unroll
        for (int nj = 0; nj < 4; ++nj)
            bf[nj] = *(const bf16x8*)((const char*)&Bs[0][0] + (wn*64 + nj*16 + l15) * 80 + l4*16);
#pragma unroll
        for (int mi = 0; mi < 2; ++mi)
#pragma unroll
            for (int nj = 0; nj < 4; ++nj)
                acc[mi][nj] = MFMA(af[mi], bf[nj], acc[mi][nj]);
    }

#pragma unroll
    for (int nj = 0; nj < 4; ++nj) {
        const int nglob = n0 + wn*64 + nj*16 + l15;
        const float bn = bias[nglob];
#pragma unroll
        for (int mi = 0; mi < 2; ++mi) {
            const int mbase = m0 + wm*32 + mi*16 + l4*4;
            if (mode == 0) {
#pragma unroll
                for (int r = 0; r < 4; ++r)
                    ((short*)C)[(size_t)(mbase + r) * 1024 + nglob] = f2bf(acc[mi][nj][r] + bn);
            } else if (mode == 1) {
                bf16x4 pk;
#pragma unroll
                for (int r = 0; r < 4; ++r) pk[r] = f2bf(acc[mi][nj][r] + bn);
                *(bf16x4*)((short*)C + (size_t)nglob * Mrows + mbase) = pk;
            } else {
#pragma unroll
                for (int r = 0; r < 4; ++r)
                    ((float*)C)[(size_t)(mbase + r) * 1024 + nglob] = acc[mi][nj][r] + bn;
            }
        }
    }
}

// ---------------------------------------------------------------------------
// phi2 (MFMA): per block = one (src, head, 64 s-rows)
// ---------------------------------------------------------------------------
__global__ __launch_bounds__(256)
void phi2_kernel(const short* __restrict__ qbuf, const short* __restrict__ kbuf,
                 const short* __restrict__ omtb, const float* __restrict__ rffb,
                 short* __restrict__ Qa, short* __restrict__ Ka)
{
    __shared__ short om[128][72];
    __shared__ float bsh[128];

    const int src = blockIdx.z, h = blockIdx.y;
    const int s0 = blockIdx.x * 64;
    const short* X = src ? kbuf : qbuf;
    short* Out     = src ? Ka : Qa;
    const float fq   = src ? 1.0f : (ALPHA * 0.125f);
    const float fphi = src ? 1.0f : ((1.0f - ALPHA) * 0.125f);

    const int tid = threadIdx.x, wave = tid >> 6, lane = tid & 63;
    const int l15 = lane & 15, l4 = lane >> 4;

    {
        const char* gsrc = (const char*)(omtb + ((size_t)h << 13));
#pragma unroll
        for (int it = 0; it < 4; ++it) {
            int f = tid * 16 + it * 4096;
            int row = f >> 7, colb = f & 127;
            *(int4v*)((char*)&om[0][0] + row * 144 + colb) = *(const int4v*)(gsrc + f);
        }
        if (tid < 128) bsh[tid] = rffb[h * 128 + tid];
    }
    __syncthreads();

    const int srow = s0 + wave * 16 + l15;

    bf16x8 xf[2];
#pragma unroll
    for (int cs = 0; cs < 2; ++cs)
        xf[cs] = *(const bf16x8*)(X + (size_t)srow * HID + h * HD + cs * 32 + l4 * 8);

    float ss = 0.f;
#pragma unroll
    for (int cs = 0; cs < 2; ++cs)
#pragma unroll
        for (int j = 0; j < 8; ++j) { float v = bf2f(xf[cs][j]); ss = fmaf(v, v, ss); }
    ss += __shfl_xor(ss, 16);
    ss += __shfl_xor(ss, 32);
    const float inv = 1.0f / (sqrtf(ss) + 1e-6f);

    bf16x8 qn[2];
#pragma unroll
    for (int cs = 0; cs < 2; ++cs) {
        bf16x8 o, w;
#pragma unroll
        for (int j = 0; j < 8; ++j) {
            float v = bf2f(xf[cs][j]);
            o[j] = f2bf(v * inv);
            w[j] = f2bf(v * fq);
        }
        qn[cs] = o;
        *(bf16x8*)(Out + ((size_t)h * S_LEN + srow) * CAUG + cs * 32 + l4 * 8) = w;
    }

    f32x4 pacc[8];
#pragma unroll
    for (int t = 0; t < 8; ++t) pacc[t] = (f32x4){0.f,0.f,0.f,0.f};
#pragma unroll
    for (int t = 0; t < 8; ++t)
#pragma unroll
        for (int cs = 0; cs < 2; ++cs) {
            bf16x8 bf = *(const bf16x8*)((const char*)&om[0][0] + (t*16 + l15) * 144 + cs*64 + l4*16);
            pacc[t] = MFMA(qn[cs], bf, pacc[t]);
        }

    float ph[8][4];
    float ps[4] = {0.f, 0.f, 0.f, 0.f};
#pragma unroll
    for (int t = 0; t < 8; ++t) {
        const float bv = bsh[t * 16 + l15];
#pragma unroll
        for (int r = 0; r < 4; ++r) {
            float p = pacc[t][r] + bv;
            float c = 0.125f * __cosf(p);
            ph[t][r] = c;
            ps[r] = fmaf(c, c, ps[r]);
        }
    }
#pragma unroll
    for (int r = 0; r < 4; ++r) {
        ps[r] += __shfl_xor(ps[r], 1);
        ps[r] += __shfl_xor(ps[r], 2);
        ps[r] += __shfl_xor(ps[r], 4);
        ps[r] += __shfl_xor(ps[r], 8);
    }
    float inv2[4];
#pragma unroll
    for (int r = 0; r < 4; ++r) inv2[r] = fphi / (sqrtf(ps[r]) + 1e-6f);

#pragma unroll
    for (int t = 0; t < 8; ++t)
#pragma unroll
        for (int r = 0; r < 4; ++r)
            Out[((size_t)h * S_LEN + s0 + wave * 16 + l4 * 4 + r) * CAUG + 64 + t * 16 + l15]
                = f2bf(ph[t][r] * inv2[r]);
}

// ---------------------------------------------------------------------------
// MFMA flash attention, WAVE-AUTONOMOUS + qj=4 (LDS-traffic-minimized).
// Block = 64 q rows; each of 4 waves covers ALL 64 q (qj=4) over a private
// quarter of K (16 chunks of 32 kpos).  Per-wave XOR-swizzled Kbuf staged via
// registers in half-chunks (T14: load early / write after the reads of the
// region complete); V direct global->reg; P in per-wave swizzled slab.
// ZERO barriers in the main loop.  Static-max softmax (fi-sequential to keep
// sacc at 16 VGPRs).  Partials combined via LDS at the end (2 barriers).
// Grid 32x16 = 512 blocks = 2 blocks/CU (LDS 64 KB, VGPR capped 256).
// ---------------------------------------------------------------------------
__global__ __launch_bounds__(256, 2)
void flash_mfma(const short* __restrict__ Qa, const short* __restrict__ Ka,
                const short* __restrict__ vt, const float* __restrict__ mask,
                short* __restrict__ ctxb)
{
    // [0,49152):     Kbuf[wave][12288]  384B rows, byte ^= ((row&7)<<4)
    // [49152,65536): P[wave][4096]      64B rows,  byte ^= ((row&3)<<4)
    // combine: scrO f32[3][64][64] @ 0; scrL f32[3][64] @ 49152
    __shared__ char smem[65536];

    const int tid = threadIdx.x;
    const int wave = tid >> 6, lane = tid & 63;
    const int l15 = lane & 15, l4 = lane >> 4;
    const int h = blockIdx.y;
    const int q0 = blockIdx.x * 64;

    char* Kbuf = smem + wave * 12288;
    char* Pb   = smem + 49152 + wave * 4096;

    // Q' fragments: all 64 q rows of the tile (qj=4)
    bf16x8 qf[4][6];
#pragma unroll
    for (int qj = 0; qj < 4; ++qj)
#pragma unroll
        for (int cs = 0; cs < 6; ++cs)
            qf[qj][cs] = *(const bf16x8*)(Qa + ((size_t)h * 2048 + q0 + qj*16 + l15) * CAUG + cs*32 + l4*8);

    f32x4 oacc[4][4];     // [di][qj]
#pragma unroll
    for (int di = 0; di < 4; ++di)
#pragma unroll
        for (int qj = 0; qj < 4; ++qj) oacc[di][qj] = (f32x4){0.f,0.f,0.f,0.f};
    float lsum[4] = {0.f, 0.f, 0.f, 0.f};

    const char* Kg = (const char*)(Ka + (size_t)h * 2048 * CAUG);   // rows 384B
    const char* Vg = (const char*)(vt + (size_t)h * 64 * 2048);     // rows 4096B
    const int c0 = wave * 16;

    // swizzled LDS write offsets for one half-chunk (6144B, 6 x 16B per lane)
    int wrA[6];
#pragma unroll
    for (int it = 0; it < 6; ++it) {
        int p = it * 1024 + lane * 16;
        int row = p / 384;
        int col = p - row * 384;
        wrA[it] = row * 384 + (col ^ ((row & 7) << 4));
    }

    int4v kpre[6];
    bf16x8 va[4];

    auto loadKhalf = [&](int kt, int half) {
        const char* kb = Kg + (size_t)kt * 12288 + half * 6144;
#pragma unroll
        for (int it = 0; it < 6; ++it)
            kpre[it] = *(const int4v*)(kb + it * 1024 + lane * 16);
    };
    auto writeKhalf = [&](int half) {
        char* b = Kbuf + half * 6144;   // +16 rows preserves row&7 -> same swizzle
#pragma unroll
        for (int it = 0; it < 6; ++it)
            *(int4v*)(b + wrA[it]) = kpre[it];
    };
    auto loadV = [&](int kt) {
#pragma unroll
        for (int di = 0; di < 4; ++di)
            va[di] = *(const bf16x8*)(Vg + (size_t)(di*16 + l15)*4096 + kt*64 + l4*16);
    };

    // prologue: stage chunk c0, load V(c0)
    loadKhalf(c0, 0); writeKhalf(0);
    loadKhalf(c0, 1); writeKhalf(1);
    loadV(c0);

    for (int i = 0; i < 16; ++i) {
        const int kt = c0 + i;
        const bool more = (i + 1 < 16);
        if (more) loadKhalf(kt + 1, 0);       // issue early; written after fi0 reads

#pragma unroll
        for (int fi = 0; fi < 2; ++fi) {
            // ---- scores fi: 32x(16 kpos) x 64 q ----
            f32x4 sacc[4];
#pragma unroll
            for (int qj = 0; qj < 4; ++qj) sacc[qj] = (f32x4){0.f,0.f,0.f,0.f};
            const int r = fi * 16 + l15;
            const int sw = (l15 & 7) << 4;    // (r&7)<<4 == (l15&7)<<4
#pragma unroll
            for (int cs = 0; cs < 6; ++cs) {
                bf16x8 ka = *(const bf16x8*)(Kbuf + r * 384 + ((cs*64 + l4*16) ^ sw));
#pragma unroll
                for (int qj = 0; qj < 4; ++qj)
                    sacc[qj] = MFMA(ka, qf[qj][cs], sacc[qj]);
            }
            // ---- static-max softmax: p = exp(s + mask); write P slab ----
            float4 mk = *(const float4*)&mask[kt*32 + fi*16 + l4*4];
            float mv[4] = {mk.x * -10000.f, mk.y * -10000.f, mk.z * -10000.f, mk.w * -10000.f};
#pragma unroll
            for (int qj = 0; qj < 4; ++qj) {
                bf16x4 pk;
#pragma unroll
                for (int rr = 0; rr < 4; ++rr) {
                    float p = __expf(sacc[qj][rr] + mv[rr]);
                    lsum[qj] += p;
                    pk[rr] = f2bf(p);
                }
                const int prow = qj*16 + l15;
                *(bf16x4*)(Pb + prow*64 + ((fi*32 + l4*8) ^ ((prow & 3) << 4))) = pk;
            }
            // stage next chunk's half over the rows just consumed
            asm volatile("" ::: "memory");
            if (more) {
                writeKhalf(fi);
                if (fi == 0) loadKhalf(kt + 1, 1);
            }
        }

        // ---- PV: O^T += V^T . P^T ----
#pragma unroll
        for (int qj = 0; qj < 4; ++qj) {
            const int prow = qj*16 + l15;
            bf16x8 pb = *(const bf16x8*)(Pb + prow*64 + ((l4*16) ^ ((prow & 3) << 4)));
#pragma unroll
            for (int di = 0; di < 4; ++di)
                oacc[di][qj] = MFMA(va[di], pb, oacc[di][qj]);
        }
        if (more) loadV(kt + 1);
    }

    // reduce l across the 4 kpos lane-groups
#pragma unroll
    for (int qj = 0; qj < 4; ++qj) {
        lsum[qj] += __shfl_xor(lsum[qj], 16);
        lsum[qj] += __shfl_xor(lsum[qj], 32);
    }

    // ---- combine the 4 wave partials via LDS (reuse Kbuf / P regions) ----
    __syncthreads();
    float* scrO = (float*)smem;              // [3][64 q][64 d] f32 = 49152 B
    float* scrL = (float*)(smem + 49152);    // [3][64] f32
    if (wave > 0) {
#pragma unroll
        for (int qj = 0; qj < 4; ++qj) {
            const int q = qj*16 + l15;
#pragma unroll
            for (int di = 0; di < 4; ++di)
                *(f32x4*)&scrO[(size_t)((wave-1)*64 + q)*64 + di*16 + l4*4] = oacc[di][qj];
            if (l4 == 0) scrL[(wave-1)*64 + q] = lsum[qj];
        }
    }
    __syncthreads();
    if (wave == 0) {
#pragma unroll
        for (int qj = 0; qj < 4; ++qj) {
            const int q = qj*16 + l15;
            float l = lsum[qj];
#pragma unroll
            for (int k = 0; k < 3; ++k) l += scrL[k*64 + q];
            const float inv = 1.0f / l;
#pragma unroll
            for (int di = 0; di < 4; ++di) {
                f32x4 o = oacc[di][qj];
#pragma unroll
                for (int k = 0; k < 3; ++k)
                    o += *(const f32x4*)&scrO[(size_t)(k*64 + q)*64 + di*16 + l4*4];
                bf16x4 ob;
#pragma unroll
                for (int r = 0; r < 4; ++r) ob[r] = f2bf(o[r] * inv);
                *(bf16x4*)(ctxb + (size_t)(q0 + q) * HID + h*64 + di*16 + l4*4) = ob;
            }
        }
    }
}

// ---------------------------------------------------------------------------
extern "C" void kernel_launch(void* const* d_in, const int* in_sizes, int n_in,
                              void* d_out, int out_size, void* d_ws, size_t ws_size,
                              hipStream_t stream)
{
    const float* hs    = (const float*)d_in[0];
    const float* mask  = (const float*)d_in[1];
    const float* Wq    = (const float*)d_in[2];
    const float* bq    = (const float*)d_in[3];
    const float* Wk    = (const float*)d_in[4];
    const float* bk    = (const float*)d_in[5];
    const float* Wv    = (const float*)d_in[6];
    const float* bv    = (const float*)d_in[7];
    const float* Wo    = (const float*)d_in[8];
    const float* bo    = (const float*)d_in[9];
    const float* omega = (const float*)d_in[10];
    const float* rffb  = (const float*)d_in[11];
    float* out = (float*)d_out;

    short* wsS = (short*)d_ws;
    short* hsb = wsS;                       // 2,097,152
    short* wqb = hsb + 2097152;             // 1,048,576
    short* wkb = wqb + 1048576;
    short* wvb = wkb + 1048576;
    short* wob = wvb + 1048576;
    short* qb  = wob + 1048576;             // 2,097,152
    short* kb  = qb  + 2097152;
    short* vtb = kb  + 2097152;             // 2,097,152  [h][d][s]
    short* ctxb= vtb + 2097152;             // 2,097,152
    short* QaB = ctxb+ 2097152;             // 6,291,456  [h][s][192]
    short* KaB = QaB + 6291456;
    short* omtb= KaB + 6291456;             // 131,072    [h][m][d]

    conv_kernel<<<6272, 256, 0, stream>>>(hs, Wq, Wk, Wv, Wo, omega,
                                          hsb, wqb, wkb, wvb, wob, omtb);
    gemm_mfma<<<dim3(8, 32, 3), 256, 0, stream>>>(hsb, wqb, bq, qb, wkb, bk, kb, wvb, bv, vtb,
                                                  0, 0, 1, S_LEN);
    phi2_kernel<<<dim3(32, 16, 2), 256, 0, stream>>>(qb, kb, omtb, rffb, QaB, KaB);
    flash_mfma<<<dim3(32, 16), 256, 0, stream>>>(QaB, KaB, vtb, mask, ctxb);
    gemm_mfma<<<dim3(8, 32, 1), 256, 0, stream>>>(ctxb, wob, bo, out, wob, bo, out, wob, bo, out,
                                                  2, 2, 2, S_LEN);
}